// Round 2
// baseline (350.854 us; speedup 1.0000x reference)
//
#include <hip/hip_runtime.h>
#include <hip/hip_cooperative_groups.h>
#include <stdint.h>

namespace cg = cooperative_groups;

static constexpr int BLOCK = 256;
static constexpr int ITEMS = 16;
static constexpr int CHUNK = BLOCK * ITEMS;   // 4096 elements per block
static constexpr int MAXNB = 512;             // 512 * 4096 = 2097152 = N

#define GAMMA_F 0.99f
static __device__ __forceinline__ float gl_const() { return (float)(0.99 * 0.95); }

// ---------------- bool dtype runtime probe ----------------
// 0 = int32, 1 = uint8/bool, 2 = float32 (0.0/1.0). See round-0 notes:
// byte pattern of first 1024 bytes distinguishes the three with certainty
// for Bernoulli(0.5) data.
__device__ __forceinline__ int detect_mode(const void* term, int n_elems, int* flg) {
    int t = threadIdx.x;
    if (t == 0) { flg[0] = 0; flg[1] = 0; }
    __syncthreads();
    if (t < 256) {
        const unsigned char* p = (const unsigned char*)term;
        int i0 = 4 * t;
        if (i0 + 3 < n_elems) {
            unsigned b1 = p[i0 + 1], b2 = p[i0 + 2], b3 = p[i0 + 3];
            if (b1) atomicOr(&flg[0], 1);
            if (b2 | b3) atomicOr(&flg[1], 1);
        }
    }
    __syncthreads();
    return flg[0] ? 1 : (flg[1] ? 2 : 0);
}

__device__ __forceinline__ int load_bool1(const void* p, long i, int mode) {
    if (mode == 1) return ((const unsigned char*)p)[i] != 0;
    if (mode == 0) return ((const int*)p)[i] != 0;
    return ((const float*)p)[i] != 0.0f;
}

__device__ __forceinline__ void load_bool16(const void* p, long base, int mode, int* f) {
    if (mode == 1) {
        uint4 q = *(const uint4*)((const unsigned char*)p + base);
        unsigned w[4] = {q.x, q.y, q.z, q.w};
#pragma unroll
        for (int j = 0; j < 16; ++j) f[j] = (int)((w[j >> 2] >> ((j & 3) * 8)) & 0xffu);
    } else if (mode == 0) {
        const int4* q = (const int4*)((const int*)p + base);
#pragma unroll
        for (int k = 0; k < 4; ++k) {
            int4 v = q[k];
            f[4*k] = v.x; f[4*k+1] = v.y; f[4*k+2] = v.z; f[4*k+3] = v.w;
        }
    } else {
        const float4* q = (const float4*)((const float*)p + base);
#pragma unroll
        for (int k = 0; k < 4; ++k) {
            float4 v = q[k];
            f[4*k] = v.x != 0.f; f[4*k+1] = v.y != 0.f; f[4*k+2] = v.z != 0.f; f[4*k+3] = v.w != 0.f;
        }
    }
}

// c[j] = not_done * gamma*lambda ; d[j] = r + gamma*not_term*nv - v
__device__ __forceinline__ void compute_cd(
    const float* __restrict__ rewards, const float* __restrict__ values,
    const float* __restrict__ next_values, const void* __restrict__ term,
    const void* __restrict__ trunc, int mode, long base, int n,
    float* c, float* d, float* v)
{
    const float GL = gl_const();
    if (base + ITEMS <= n) {
        float r[ITEMS], nv[ITEMS];
        const float4* r4 = (const float4*)(rewards + base);
        const float4* v4 = (const float4*)(values + base);
        const float4* n4 = (const float4*)(next_values + base);
#pragma unroll
        for (int k = 0; k < 4; ++k) {
            float4 a = r4[k]; r[4*k]=a.x; r[4*k+1]=a.y; r[4*k+2]=a.z; r[4*k+3]=a.w;
            float4 b = v4[k]; v[4*k]=b.x; v[4*k+1]=b.y; v[4*k+2]=b.z; v[4*k+3]=b.w;
            float4 q = n4[k]; nv[4*k]=q.x; nv[4*k+1]=q.y; nv[4*k+2]=q.z; nv[4*k+3]=q.w;
        }
        int tm[ITEMS], tr[ITEMS];
        load_bool16(term,  base, mode, tm);
        load_bool16(trunc, base, mode, tr);
#pragma unroll
        for (int j = 0; j < ITEMS; ++j) {
            float nt = tm[j] ? 0.f : 1.f;
            float nd = (tm[j] | tr[j]) ? 0.f : 1.f;
            d[j] = r[j] + GAMMA_F * nt * nv[j] - v[j];
            c[j] = nd * GL;
        }
    } else {
#pragma unroll
        for (int j = 0; j < ITEMS; ++j) {
            long i = base + j;
            if (i < (long)n) {
                int tm = load_bool1(term, i, mode);
                int tr = load_bool1(trunc, i, mode);
                float nt = tm ? 0.f : 1.f;
                float nd = (tm | tr) ? 0.f : 1.f;
                v[j] = values[i];
                d[j] = rewards[i] + GAMMA_F * nt * next_values[i] - v[j];
                c[j] = nd * GL;
            } else { c[j] = 1.f; d[j] = 0.f; v[j] = 0.f; }
        }
    }
}

// Fused cooperative kernel: one pass over inputs, one write of out.
// nb blocks (<= 512), 2 blocks/CU co-resident (guaranteed by launch_bounds).
__global__ __launch_bounds__(BLOCK, 2) void ppo_fused(
    const float* __restrict__ rewards, const float* __restrict__ values,
    const float* __restrict__ next_values, const float* __restrict__ lp,
    const float* __restrict__ olp, const void* __restrict__ term,
    const void* __restrict__ trunc, float* __restrict__ out,
    float2* __restrict__ blockAgg, float* __restrict__ S,
    float2* __restrict__ blockSums, float* __restrict__ stats,
    int n, int nb)
{
    __shared__ int flg[2];
    __shared__ float sA[BLOCK], sB[BLOCK];
    __shared__ double dS[BLOCK], dS2[BLOCK];
    cg::grid_group grid = cg::this_grid();

    const int t = threadIdx.x;
    const int bid = blockIdx.x;
    const int mode = detect_mode(term, n, flg);
    const long base = (long)bid * CHUNK + (long)t * ITEMS;

    float c[ITEMS], d[ITEMS], v[ITEMS];
    compute_cd(rewards, values, next_values, term, trunc, mode, base, n, c, d, v);

    // ---- Phase A: thread-serial affine aggregate + block suffix scan ----
    float a = 1.f, b = 0.f;
#pragma unroll
    for (int j = ITEMS - 1; j >= 0; --j) { b = c[j]*b + d[j]; a = c[j]*a; }
    sA[t] = a; sB[t] = b;
    __syncthreads();
    for (int dd = 1; dd < BLOCK; dd <<= 1) {
        float ra = 1.f, rb = 0.f;
        if (t + dd < BLOCK) { ra = sA[t + dd]; rb = sB[t + dd]; }
        __syncthreads();
        b = a * rb + b;   // self ∘ right (uses pre-update a)
        a = a * ra;
        sA[t] = a; sB[t] = b;
        __syncthreads();
    }
    // Save exclusive-from-right entry function E_t = H_{t+1} into registers
    // NOW (block 0 clobbers sA/sB in phase B).
    float ea = 1.f, eb = 0.f;
    if (t + 1 < BLOCK) { ea = sA[t + 1]; eb = sB[t + 1]; }
    if (t == 0) blockAgg[bid] = make_float2(a, b);   // H_0 = whole-block aggregate

    grid.sync();

    // ---- Phase B: block 0 suffix-scans the nb (<=512) block aggregates ----
    if (bid == 0) {
        const int i0 = 2 * t, i1 = 2 * t + 1;
        float a0 = 1.f, b0 = 0.f, a1 = 1.f, b1 = 0.f;
        if (i0 < nb) { float2 f = blockAgg[i0]; a0 = f.x; b0 = f.y; }
        if (i1 < nb) { float2 f = blockAgg[i1]; a1 = f.x; b1 = f.y; }
        float fa = a0 * a1, fb = a0 * b1 + b0;       // e_{2t} ∘ e_{2t+1}
        float pa = fa, pb = fb;
        sA[t] = pa; sB[t] = pb;
        __syncthreads();
        for (int dd = 1; dd < BLOCK; dd <<= 1) {
            float ra = 1.f, rb = 0.f;
            if (t + dd < BLOCK) { ra = sA[t + dd]; rb = sB[t + dd]; }
            __syncthreads();
            pb = pa * rb + pb;
            pa = pa * ra;
            sA[t] = pa; sB[t] = pb;
            __syncthreads();
        }
        float Eb = 0.f;                               // E_t = H_{t+1} applied to 0
        if (t + 1 < BLOCK) { Eb = sB[t + 1]; }
        if (i1 < nb) S[i1] = Eb;                      // (e_{2t+2}...e_{nb-1})(0)
        if (i0 < nb) S[i0] = a1 * Eb + b1;            // e_{2t+1} ∘ E_t (0)
    }

    grid.sync();

    // ---- Phase C: replay to get adv; per-block partial sums ----
    float x = ea * S[bid] + eb;
    float adv[ITEMS];
    float s = 0.f, s2 = 0.f;
#pragma unroll
    for (int j = ITEMS - 1; j >= 0; --j) {
        x = c[j] * x + d[j];
        adv[j] = x;
        if (base + j < (long)n) { s += x; s2 += x * x; }
    }
    sA[t] = s; sB[t] = s2;      // safe: grid.sync aligned all threads
    __syncthreads();
    for (int dd = BLOCK / 2; dd > 0; dd >>= 1) {
        if (t < dd) { sA[t] += sA[t + dd]; sB[t] += sB[t + dd]; }
        __syncthreads();
    }
    if (t == 0) blockSums[bid] = make_float2(sA[0], sB[0]);

    grid.sync();

    // ---- Phase D: block 0 reduces partials -> mean, inv-std ----
    if (bid == 0) {
        double ds = 0.0, ds2 = 0.0;
        for (int i = t; i < nb; i += BLOCK) { float2 f = blockSums[i]; ds += (double)f.x; ds2 += (double)f.y; }
        dS[t] = ds; dS2[t] = ds2;
        __syncthreads();
        for (int dd = BLOCK / 2; dd > 0; dd >>= 1) {
            if (t < dd) { dS[t] += dS[t + dd]; dS2[t] += dS2[t + dd]; }
            __syncthreads();
        }
        if (t == 0) {
            double sum = dS[0], sumsq = dS2[0];
            double mean = sum / (double)n;
            double var = (sumsq - sum * sum / (double)n) / (double)(n - 1);
            if (var < 0.0) var = 0.0;
            stats[0] = (float)mean;
            stats[1] = 1.0f / ((float)sqrt(var) + 1e-9f);
        }
    }

    grid.sync();

    // ---- Phase E: normalize + actor loss; single fully-vectorized store ----
    const float mean = stats[0];
    const float inv  = stats[1];
    if (base + ITEMS <= n) {
        float l[ITEMS], o[ITEMS];
        const float4* l4 = (const float4*)(lp + base);
        const float4* o4 = (const float4*)(olp + base);
#pragma unroll
        for (int k = 0; k < 4; ++k) {
            float4 q = l4[k]; l[4*k]=q.x; l[4*k+1]=q.y; l[4*k+2]=q.z; l[4*k+3]=q.w;
            float4 w = o4[k]; o[4*k]=w.x; o[4*k+1]=w.y; o[4*k+2]=w.z; o[4*k+3]=w.w;
        }
        float buf[3 * ITEMS];
#pragma unroll
        for (int j = 0; j < ITEMS; ++j) {
            float an = (adv[j] - mean) * inv;
            float ratio = expf(l[j] - o[j]);
            float cl = fminf(fmaxf(ratio, 0.8f), 1.2f);
            buf[3*j]     = an;
            buf[3*j + 1] = adv[j] + v[j];
            buf[3*j + 2] = -fminf(ratio * an, cl * an);
        }
        float4* dst = (float4*)(out + 3 * base);   // 3*base % 4 == 0, 16B-aligned
#pragma unroll
        for (int k = 0; k < 12; ++k)
            dst[k] = make_float4(buf[4*k], buf[4*k+1], buf[4*k+2], buf[4*k+3]);
    } else {
        for (int j = 0; j < ITEMS; ++j) {
            long i = base + j;
            if (i < (long)n) {
                float an = (adv[j] - mean) * inv;
                float ratio = expf(lp[i] - olp[i]);
                float cl = fminf(fmaxf(ratio, 0.8f), 1.2f);
                out[3*i]     = an;
                out[3*i + 1] = adv[j] + v[j];
                out[3*i + 2] = -fminf(ratio * an, cl * an);
            }
        }
    }
}

extern "C" void kernel_launch(void* const* d_in, const int* in_sizes, int n_in,
                              void* d_out, int out_size, void* d_ws, size_t ws_size,
                              hipStream_t stream) {
    const float* rewards     = (const float*)d_in[0];
    const float* values      = (const float*)d_in[1];
    const float* next_values = (const float*)d_in[2];
    const float* lp          = (const float*)d_in[3];
    const float* olp         = (const float*)d_in[4];
    const void*  term        = d_in[5];
    const void*  trunc       = d_in[6];
    float* out = (float*)d_out;
    int n = in_sizes[0];
    int nb = (n + CHUNK - 1) / CHUNK;   // 512 for N=2^21; must be <= MAXNB

    char* ws = (char*)d_ws;
    float2* blockAgg  = (float2*)ws;                         // 4 KB
    float*  S         = (float*) (ws + MAXNB * 8);           // 2 KB
    float2* blockSums = (float2*)(ws + MAXNB * 8 + MAXNB * 4);
    float*  stats     = (float*) (ws + MAXNB * 8 + MAXNB * 4 + MAXNB * 8);

    void* args[] = { &rewards, &values, &next_values, &lp, &olp, &term, &trunc,
                     &out, &blockAgg, &S, &blockSums, &stats, &n, &nb };
    hipLaunchCooperativeKernel((void*)ppo_fused, dim3(nb), dim3(BLOCK),
                               args, 0, stream);
}

// Round 3
// 136.124 us; speedup vs baseline: 2.5775x; 2.5775x over previous
//
#include <hip/hip_runtime.h>
#include <stdint.h>

static constexpr int BLOCK = 256;
static constexpr int ITEMS = 8;
static constexpr int CHUNK = BLOCK * ITEMS;   // 2048 elements per block
static constexpr int MAXNB = 1024;            // 1024 * 2048 = 2097152 = N

#define GAMMA_F 0.99f
static __device__ __forceinline__ float gl_const() { return (float)(0.99 * 0.95); }

// ---------------- bool dtype runtime probe ----------------
// 0 = int32, 1 = uint8/bool, 2 = float32 (0.0/1.0). Byte pattern of the
// first 1024 bytes distinguishes the three with certainty for Bernoulli data.
__device__ __forceinline__ int detect_mode(const void* term, int n_elems, int* flg) {
    int t = threadIdx.x;
    if (t == 0) { flg[0] = 0; flg[1] = 0; }
    __syncthreads();
    if (t < 256) {
        const unsigned char* p = (const unsigned char*)term;
        int i0 = 4 * t;
        if (i0 + 3 < n_elems) {
            unsigned b1 = p[i0 + 1], b2 = p[i0 + 2], b3 = p[i0 + 3];
            if (b1) atomicOr(&flg[0], 1);
            if (b2 | b3) atomicOr(&flg[1], 1);
        }
    }
    __syncthreads();
    return flg[0] ? 1 : (flg[1] ? 2 : 0);
}

__device__ __forceinline__ int load_bool1(const void* p, long i, int mode) {
    if (mode == 1) return ((const unsigned char*)p)[i] != 0;
    if (mode == 0) return ((const int*)p)[i] != 0;
    return ((const float*)p)[i] != 0.0f;
}

__device__ __forceinline__ void load_bool8(const void* p, long base, int mode, int* f) {
    if (mode == 1) {
        uint2 q = *(const uint2*)((const unsigned char*)p + base);
        unsigned w[2] = {q.x, q.y};
#pragma unroll
        for (int j = 0; j < 8; ++j) f[j] = (int)((w[j >> 2] >> ((j & 3) * 8)) & 0xffu);
    } else if (mode == 0) {
        const int4* q = (const int4*)((const int*)p + base);
#pragma unroll
        for (int k = 0; k < 2; ++k) {
            int4 v = q[k];
            f[4*k] = v.x; f[4*k+1] = v.y; f[4*k+2] = v.z; f[4*k+3] = v.w;
        }
    } else {
        const float4* q = (const float4*)((const float*)p + base);
#pragma unroll
        for (int k = 0; k < 2; ++k) {
            float4 v = q[k];
            f[4*k] = v.x != 0.f; f[4*k+1] = v.y != 0.f; f[4*k+2] = v.z != 0.f; f[4*k+3] = v.w != 0.f;
        }
    }
}

// c[j] = not_done * gamma*lambda ; d[j] = r + gamma*not_term*nv - v
__device__ __forceinline__ void compute_cd(
    const float* __restrict__ rewards, const float* __restrict__ values,
    const float* __restrict__ next_values, const void* __restrict__ term,
    const void* __restrict__ trunc, int mode, long base, int n,
    float* c, float* d, float* v)
{
    const float GL = gl_const();
    if (base + ITEMS <= n) {
        float r[ITEMS], nv[ITEMS];
        const float4* r4 = (const float4*)(rewards + base);
        const float4* v4 = (const float4*)(values + base);
        const float4* n4 = (const float4*)(next_values + base);
#pragma unroll
        for (int k = 0; k < 2; ++k) {
            float4 a = r4[k]; r[4*k]=a.x; r[4*k+1]=a.y; r[4*k+2]=a.z; r[4*k+3]=a.w;
            float4 b = v4[k]; v[4*k]=b.x; v[4*k+1]=b.y; v[4*k+2]=b.z; v[4*k+3]=b.w;
            float4 q = n4[k]; nv[4*k]=q.x; nv[4*k+1]=q.y; nv[4*k+2]=q.z; nv[4*k+3]=q.w;
        }
        int tm[ITEMS], tr[ITEMS];
        load_bool8(term,  base, mode, tm);
        load_bool8(trunc, base, mode, tr);
#pragma unroll
        for (int j = 0; j < ITEMS; ++j) {
            float nt = tm[j] ? 0.f : 1.f;
            float nd = (tm[j] | tr[j]) ? 0.f : 1.f;
            d[j] = r[j] + GAMMA_F * nt * nv[j] - v[j];
            c[j] = nd * GL;
        }
    } else {
#pragma unroll
        for (int j = 0; j < ITEMS; ++j) {
            long i = base + j;
            if (i < (long)n) {
                int tm = load_bool1(term, i, mode);
                int tr = load_bool1(trunc, i, mode);
                float nt = tm ? 0.f : 1.f;
                float nd = (tm | tr) ? 0.f : 1.f;
                v[j] = values[i];
                d[j] = rewards[i] + GAMMA_F * nt * next_values[i] - v[j];
                c[j] = nd * GL;
            } else { c[j] = 1.f; d[j] = 0.f; v[j] = 0.f; }
        }
    }
}

// ---------------- K1: per-block affine aggregate ----------------
__global__ __launch_bounds__(BLOCK) void k1_agg(
    const float* __restrict__ rewards, const float* __restrict__ values,
    const float* __restrict__ next_values, const void* __restrict__ term,
    const void* __restrict__ trunc, float2* __restrict__ blockAgg, int n)
{
    __shared__ int flg[2];
    __shared__ float sA[BLOCK], sB[BLOCK];
    int mode = detect_mode(term, n, flg);
    int t = threadIdx.x;
    long base = (long)blockIdx.x * CHUNK + (long)t * ITEMS;
    float c[ITEMS], d[ITEMS], v[ITEMS];
    compute_cd(rewards, values, next_values, term, trunc, mode, base, n, c, d, v);
    float a = 1.f, b = 0.f;
#pragma unroll
    for (int j = ITEMS - 1; j >= 0; --j) { b = c[j]*b + d[j]; a = c[j]*a; }
    sA[t] = a; sB[t] = b;
    __syncthreads();
    for (int dd = 1; dd < BLOCK; dd <<= 1) {
        float ra = 1.f, rb = 0.f;
        if (t + dd < BLOCK) { ra = sA[t + dd]; rb = sB[t + dd]; }
        __syncthreads();
        b = a * rb + b;   // self ∘ right (uses pre-update a)
        a = a * ra;
        sA[t] = a; sB[t] = b;
        __syncthreads();
    }
    if (t == 0) blockAgg[blockIdx.x] = make_float2(a, b);
}

// ---------------- K2: suffix scan of up to 1024 block aggregates ----------------
// 256 threads, 4 aggregates per thread.
__global__ __launch_bounds__(BLOCK) void k2_scan(
    const float2* __restrict__ blockAgg, float* __restrict__ S, int nb)
{
    __shared__ float sA[BLOCK], sB[BLOCK];
    const int t = threadIdx.x;
    float la[4], lb[4];
#pragma unroll
    for (int j = 0; j < 4; ++j) {
        int i = 4 * t + j;
        if (i < nb) { float2 f = blockAgg[i]; la[j] = f.x; lb[j] = f.y; }
        else        { la[j] = 1.f; lb[j] = 0.f; }
    }
    // g_t = e_{4t} ∘ e_{4t+1} ∘ e_{4t+2} ∘ e_{4t+3}
    float a = 1.f, b = 0.f;
#pragma unroll
    for (int j = 3; j >= 0; --j) { b = la[j] * b + lb[j]; a = la[j] * a; }
    sA[t] = a; sB[t] = b;
    __syncthreads();
    for (int dd = 1; dd < BLOCK; dd <<= 1) {
        float ra = 1.f, rb = 0.f;
        if (t + dd < BLOCK) { ra = sA[t + dd]; rb = sB[t + dd]; }
        __syncthreads();
        b = a * rb + b;
        a = a * ra;
        sA[t] = a; sB[t] = b;
        __syncthreads();
    }
    // E_t = H_{t+1} (identity for t=255); S[i] = F_{i+1}(0), S[i-1]=e_i(S[i])
    float x = (t + 1 < BLOCK) ? sB[t + 1] : 0.f;
    if (4 * t + 3 < nb) S[4 * t + 3] = x;
    x = la[3] * x + lb[3];
    if (4 * t + 2 < nb) S[4 * t + 2] = x;
    x = la[2] * x + lb[2];
    if (4 * t + 1 < nb) S[4 * t + 1] = x;
    x = la[1] * x + lb[1];
    if (4 * t     < nb) S[4 * t    ] = x;
}

// ---------------- K3: replay -> advs scratch; per-block sums ----------------
__global__ __launch_bounds__(BLOCK) void k3_adv(
    const float* __restrict__ rewards, const float* __restrict__ values,
    const float* __restrict__ next_values, const void* __restrict__ term,
    const void* __restrict__ trunc, const float* __restrict__ S,
    float* __restrict__ advs, float2* __restrict__ blockSums, int n)
{
    __shared__ int flg[2];
    __shared__ float sA[BLOCK], sB[BLOCK];
    int mode = detect_mode(term, n, flg);
    int t = threadIdx.x;
    long base = (long)blockIdx.x * CHUNK + (long)t * ITEMS;
    float c[ITEMS], d[ITEMS], v[ITEMS];
    compute_cd(rewards, values, next_values, term, trunc, mode, base, n, c, d, v);
    float a = 1.f, b = 0.f;
#pragma unroll
    for (int j = ITEMS - 1; j >= 0; --j) { b = c[j]*b + d[j]; a = c[j]*a; }
    sA[t] = a; sB[t] = b;
    __syncthreads();
    for (int dd = 1; dd < BLOCK; dd <<= 1) {
        float ra = 1.f, rb = 0.f;
        if (t + dd < BLOCK) { ra = sA[t + dd]; rb = sB[t + dd]; }
        __syncthreads();
        b = a * rb + b;
        a = a * ra;
        sA[t] = a; sB[t] = b;
        __syncthreads();
    }
    float ea = 1.f, eb = 0.f;
    if (t + 1 < BLOCK) { ea = sA[t + 1]; eb = sB[t + 1]; }
    float x = ea * S[blockIdx.x] + eb;
    float adv[ITEMS];
    float s = 0.f, s2 = 0.f;
#pragma unroll
    for (int j = ITEMS - 1; j >= 0; --j) {
        x = c[j] * x + d[j];
        adv[j] = x;
        if (base + j < (long)n) { s += x; s2 += x * x; }
    }
    if (base + ITEMS <= n) {
        float4* dst = (float4*)(advs + base);
        dst[0] = make_float4(adv[0], adv[1], adv[2], adv[3]);
        dst[1] = make_float4(adv[4], adv[5], adv[6], adv[7]);
    } else {
        for (int j = 0; j < ITEMS; ++j)
            if (base + j < (long)n) advs[base + j] = adv[j];
    }
    __syncthreads();
    sA[t] = s; sB[t] = s2;
    __syncthreads();
    for (int dd = BLOCK / 2; dd > 0; dd >>= 1) {
        if (t < dd) { sA[t] += sA[t + dd]; sB[t] += sB[t + dd]; }
        __syncthreads();
    }
    if (t == 0) blockSums[blockIdx.x] = make_float2(sA[0], sB[0]);
}

// ---------------- K3b: reduce block sums -> mean, inv-std ----------------
__global__ __launch_bounds__(BLOCK) void k3b_stats(
    const float2* __restrict__ blockSums, float* __restrict__ stats, int nb, int n)
{
    __shared__ double dS[BLOCK], dS2[BLOCK];
    const int t = threadIdx.x;
    double s = 0.0, s2 = 0.0;
    for (int i = t; i < nb; i += BLOCK) {
        float2 f = blockSums[i];
        s += (double)f.x; s2 += (double)f.y;
    }
    dS[t] = s; dS2[t] = s2;
    __syncthreads();
    for (int dd = BLOCK / 2; dd > 0; dd >>= 1) {
        if (t < dd) { dS[t] += dS[t + dd]; dS2[t] += dS2[t + dd]; }
        __syncthreads();
    }
    if (t == 0) {
        double sum = dS[0], sumsq = dS2[0];
        double mean = sum / (double)n;
        double var = (sumsq - sum * sum / (double)n) / (double)(n - 1);
        if (var < 0.0) var = 0.0;
        stats[0] = (float)mean;
        stats[1] = 1.0f / ((float)sqrt(var) + 1e-9f);
    }
}

// ---------------- K4: finalize; pure vectorized stores, no RMW ----------------
__global__ __launch_bounds__(BLOCK) void k4_final(
    const float* __restrict__ advs, const float* __restrict__ values,
    const float* __restrict__ lp, const float* __restrict__ olp,
    const float* __restrict__ stats, float* __restrict__ out, int n)
{
    long e = ((long)blockIdx.x * blockDim.x + threadIdx.x) * 4;
    if (e >= n) return;
    const float mean = stats[0];
    const float inv  = stats[1];
    if (e + 4 <= n) {
        float4 a4 = *(const float4*)(advs + e);
        float4 v4 = *(const float4*)(values + e);
        float4 l4 = *(const float4*)(lp + e);
        float4 o4 = *(const float4*)(olp + e);
        float av[4] = {a4.x, a4.y, a4.z, a4.w};
        float vv[4] = {v4.x, v4.y, v4.z, v4.w};
        float lv[4] = {l4.x, l4.y, l4.z, l4.w};
        float ov[4] = {o4.x, o4.y, o4.z, o4.w};
        float buf[12];
#pragma unroll
        for (int j = 0; j < 4; ++j) {
            float an = (av[j] - mean) * inv;
            float ratio = expf(lv[j] - ov[j]);
            float cl = fminf(fmaxf(ratio, 0.8f), 1.2f);
            buf[3*j]     = an;
            buf[3*j + 1] = av[j] + vv[j];
            buf[3*j + 2] = -fminf(ratio * an, cl * an);
        }
        float4* dst = (float4*)(out + 3 * e);   // 3*e % 4 == 0 → 16B aligned
        dst[0] = make_float4(buf[0], buf[1], buf[2],  buf[3]);
        dst[1] = make_float4(buf[4], buf[5], buf[6],  buf[7]);
        dst[2] = make_float4(buf[8], buf[9], buf[10], buf[11]);
    } else {
        for (long i = e; i < (long)n; ++i) {
            float a = advs[i];
            float an = (a - mean) * inv;
            float ratio = expf(lp[i] - olp[i]);
            float cl = fminf(fmaxf(ratio, 0.8f), 1.2f);
            out[3*i]     = an;
            out[3*i + 1] = a + values[i];
            out[3*i + 2] = -fminf(ratio * an, cl * an);
        }
    }
}

extern "C" void kernel_launch(void* const* d_in, const int* in_sizes, int n_in,
                              void* d_out, int out_size, void* d_ws, size_t ws_size,
                              hipStream_t stream) {
    const float* rewards     = (const float*)d_in[0];
    const float* values      = (const float*)d_in[1];
    const float* next_values = (const float*)d_in[2];
    const float* lp          = (const float*)d_in[3];
    const float* olp         = (const float*)d_in[4];
    const void*  term        = d_in[5];
    const void*  trunc       = d_in[6];
    float* out = (float*)d_out;
    int n = in_sizes[0];
    int nb = (n + CHUNK - 1) / CHUNK;   // 1024 for N=2^21; must be <= MAXNB

    char* ws = (char*)d_ws;
    size_t advs_bytes = (((size_t)n * 4) + 255) & ~(size_t)255;
    float*  advs      = (float*)ws;
    float2* blockAgg  = (float2*)(ws + advs_bytes);
    float*  S         = (float*)(ws + advs_bytes + MAXNB * 8);
    float2* blockSums = (float2*)(ws + advs_bytes + MAXNB * 8 + MAXNB * 4);
    float*  stats     = (float*)(ws + advs_bytes + MAXNB * 8 + MAXNB * 4 + MAXNB * 8);

    k1_agg   <<<nb, BLOCK, 0, stream>>>(rewards, values, next_values, term, trunc, blockAgg, n);
    k2_scan  <<<1,  BLOCK, 0, stream>>>(blockAgg, S, nb);
    k3_adv   <<<nb, BLOCK, 0, stream>>>(rewards, values, next_values, term, trunc, S, advs, blockSums, n);
    k3b_stats<<<1,  BLOCK, 0, stream>>>(blockSums, stats, nb, n);
    int n4blocks = (int)(((long)n / 4 + BLOCK - 1) / BLOCK);
    k4_final <<<n4blocks, BLOCK, 0, stream>>>(advs, values, lp, olp, stats, out, n);
}

// Round 4
// 130.917 us; speedup vs baseline: 2.6800x; 1.0398x over previous
//
#include <hip/hip_runtime.h>
#include <stdint.h>

static constexpr int BLOCK = 256;
static constexpr int ITEMS = 8;
static constexpr int CHUNK = BLOCK * ITEMS;   // 2048 elements per block
static constexpr int MAXNB = 1024;            // 1024 * 2048 = 2097152 = N

#define GAMMA_F 0.99f
static __device__ __forceinline__ float gl_const() { return (float)(0.99 * 0.95); }

// ---------------- bool dtype runtime probe ----------------
// 0 = int32, 1 = uint8/bool, 2 = float32. Byte pattern of first 1024 bytes.
__device__ __forceinline__ int detect_mode(const void* term, int n_elems, int* flg) {
    int t = threadIdx.x;
    if (t == 0) { flg[0] = 0; flg[1] = 0; }
    __syncthreads();
    if (t < 256) {
        const unsigned char* p = (const unsigned char*)term;
        int i0 = 4 * t;
        if (i0 + 3 < n_elems) {
            unsigned b1 = p[i0 + 1], b2 = p[i0 + 2], b3 = p[i0 + 3];
            if (b1) atomicOr(&flg[0], 1);
            if (b2 | b3) atomicOr(&flg[1], 1);
        }
    }
    __syncthreads();
    return flg[0] ? 1 : (flg[1] ? 2 : 0);
}

__device__ __forceinline__ int load_bool1(const void* p, long i, int mode) {
    if (mode == 1) return ((const unsigned char*)p)[i] != 0;
    if (mode == 0) return ((const int*)p)[i] != 0;
    return ((const float*)p)[i] != 0.0f;
}

__device__ __forceinline__ void load_bool8(const void* p, long base, int mode, int* f) {
    if (mode == 1) {
        uint2 q = *(const uint2*)((const unsigned char*)p + base);
        unsigned w[2] = {q.x, q.y};
#pragma unroll
        for (int j = 0; j < 8; ++j) f[j] = (int)((w[j >> 2] >> ((j & 3) * 8)) & 0xffu);
    } else if (mode == 0) {
        const int4* q = (const int4*)((const int*)p + base);
#pragma unroll
        for (int k = 0; k < 2; ++k) {
            int4 v = q[k];
            f[4*k] = v.x; f[4*k+1] = v.y; f[4*k+2] = v.z; f[4*k+3] = v.w;
        }
    } else {
        const float4* q = (const float4*)((const float*)p + base);
#pragma unroll
        for (int k = 0; k < 2; ++k) {
            float4 v = q[k];
            f[4*k] = v.x != 0.f; f[4*k+1] = v.y != 0.f; f[4*k+2] = v.z != 0.f; f[4*k+3] = v.w != 0.f;
        }
    }
}

// c[j] = not_done * gamma*lambda ; d[j] = r + gamma*not_term*nv - v
__device__ __forceinline__ void compute_cd(
    const float* __restrict__ rewards, const float* __restrict__ values,
    const float* __restrict__ next_values, const void* __restrict__ term,
    const void* __restrict__ trunc, int mode, long base, int n,
    float* c, float* d, float* v)
{
    const float GL = gl_const();
    if (base + ITEMS <= n) {
        float r[ITEMS], nv[ITEMS];
        const float4* r4 = (const float4*)(rewards + base);
        const float4* v4 = (const float4*)(values + base);
        const float4* n4 = (const float4*)(next_values + base);
#pragma unroll
        for (int k = 0; k < 2; ++k) {
            float4 a = r4[k]; r[4*k]=a.x; r[4*k+1]=a.y; r[4*k+2]=a.z; r[4*k+3]=a.w;
            float4 b = v4[k]; v[4*k]=b.x; v[4*k+1]=b.y; v[4*k+2]=b.z; v[4*k+3]=b.w;
            float4 q = n4[k]; nv[4*k]=q.x; nv[4*k+1]=q.y; nv[4*k+2]=q.z; nv[4*k+3]=q.w;
        }
        int tm[ITEMS], tr[ITEMS];
        load_bool8(term,  base, mode, tm);
        load_bool8(trunc, base, mode, tr);
#pragma unroll
        for (int j = 0; j < ITEMS; ++j) {
            float nt = tm[j] ? 0.f : 1.f;
            float nd = (tm[j] | tr[j]) ? 0.f : 1.f;
            d[j] = r[j] + GAMMA_F * nt * nv[j] - v[j];
            c[j] = nd * GL;
        }
    } else {
#pragma unroll
        for (int j = 0; j < ITEMS; ++j) {
            long i = base + j;
            if (i < (long)n) {
                int tm = load_bool1(term, i, mode);
                int tr = load_bool1(trunc, i, mode);
                float nt = tm ? 0.f : 1.f;
                float nd = (tm | tr) ? 0.f : 1.f;
                v[j] = values[i];
                d[j] = rewards[i] + GAMMA_F * nt * next_values[i] - v[j];
                c[j] = nd * GL;
            } else { c[j] = 1.f; d[j] = 0.f; v[j] = 0.f; }
        }
    }
}

// ---------------- K1: block aggregate + symbolic moment sums ----------------
// Per block b: every adv_i is affine in the block's incoming suffix value x_b:
//   adv_i = P_i * x_b + Q_i
// We emit the block aggregate (a,b) AND (ΣP, ΣQ, ΣP², ΣPQ, ΣQ²) so K2 can
// compute exact global mean/var analytically — advs never materialized.
__global__ __launch_bounds__(BLOCK) void k1_agg(
    const float* __restrict__ rewards, const float* __restrict__ values,
    const float* __restrict__ next_values, const void* __restrict__ term,
    const void* __restrict__ trunc, float2* __restrict__ blockAgg,
    float4* __restrict__ bs4, float* __restrict__ bs1, int n)
{
    __shared__ int flg[2];
    __shared__ float sA[BLOCK], sB[BLOCK], sC[BLOCK], sD[BLOCK], sE[BLOCK];
    int mode = detect_mode(term, n, flg);
    int t = threadIdx.x;
    long base = (long)blockIdx.x * CHUNK + (long)t * ITEMS;
    float c[ITEMS], d[ITEMS], v[ITEMS];
    compute_cd(rewards, values, next_values, term, trunc, mode, base, n, c, d, v);
    float a = 1.f, b = 0.f;
#pragma unroll
    for (int j = ITEMS - 1; j >= 0; --j) { b = c[j]*b + d[j]; a = c[j]*a; }
    sA[t] = a; sB[t] = b;
    __syncthreads();
    for (int dd = 1; dd < BLOCK; dd <<= 1) {
        float ra = 1.f, rb = 0.f;
        if (t + dd < BLOCK) { ra = sA[t + dd]; rb = sB[t + dd]; }
        __syncthreads();
        b = a * rb + b;   // self ∘ right (uses pre-update a)
        a = a * ra;
        sA[t] = a; sB[t] = b;
        __syncthreads();
    }
    // E_t = H_{t+1}: affine entry map for this thread's chunk (in terms of x_b)
    float p = 1.f, q = 0.f;
    if (t + 1 < BLOCK) { p = sA[t + 1]; q = sB[t + 1]; }
    if (t == 0) blockAgg[blockIdx.x] = make_float2(a, b);   // H_0
    // symbolic replay: adv_j = p*x_b + q after update
    float sP = 0.f, sQ = 0.f, sP2 = 0.f, sPQ = 0.f, sQ2 = 0.f;
#pragma unroll
    for (int j = ITEMS - 1; j >= 0; --j) {
        p = c[j] * p;
        q = c[j] * q + d[j];
        if (base + j < (long)n) {
            sP += p; sQ += q; sP2 += p*p; sPQ += p*q; sQ2 += q*q;
        }
    }
    __syncthreads();   // scan reads of sA/sB complete
    sA[t] = sP; sB[t] = sQ; sC[t] = sP2; sD[t] = sPQ; sE[t] = sQ2;
    __syncthreads();
    for (int dd = BLOCK / 2; dd > 0; dd >>= 1) {
        if (t < dd) {
            sA[t] += sA[t + dd]; sB[t] += sB[t + dd]; sC[t] += sC[t + dd];
            sD[t] += sD[t + dd]; sE[t] += sE[t + dd];
        }
        __syncthreads();
    }
    if (t == 0) {
        bs4[blockIdx.x] = make_float4(sA[0], sB[0], sC[0], sD[0]);
        bs1[blockIdx.x] = sE[0];
    }
}

// ---------------- K2: suffix scan of aggregates + analytic stats ----------------
__global__ __launch_bounds__(BLOCK) void k2_scan(
    const float2* __restrict__ blockAgg, const float4* __restrict__ bs4,
    const float* __restrict__ bs1, float* __restrict__ S,
    float* __restrict__ stats, int nb, int n)
{
    __shared__ float sA[BLOCK], sB[BLOCK];
    __shared__ double dS[BLOCK], dS2[BLOCK];
    const int t = threadIdx.x;
    float la[4], lb[4];
#pragma unroll
    for (int j = 0; j < 4; ++j) {
        int i = 4 * t + j;
        if (i < nb) { float2 f = blockAgg[i]; la[j] = f.x; lb[j] = f.y; }
        else        { la[j] = 1.f; lb[j] = 0.f; }
    }
    float a = 1.f, b = 0.f;
#pragma unroll
    for (int j = 3; j >= 0; --j) { b = la[j] * b + lb[j]; a = la[j] * a; }
    sA[t] = a; sB[t] = b;
    __syncthreads();
    for (int dd = 1; dd < BLOCK; dd <<= 1) {
        float ra = 1.f, rb = 0.f;
        if (t + dd < BLOCK) { ra = sA[t + dd]; rb = sB[t + dd]; }
        __syncthreads();
        b = a * rb + b;
        a = a * ra;
        sA[t] = a; sB[t] = b;
        __syncthreads();
    }
    float x = (t + 1 < BLOCK) ? sB[t + 1] : 0.f;   // suffix value entering block 4t+3
    double ds = 0.0, ds2 = 0.0;
#pragma unroll
    for (int j = 3; j >= 0; --j) {
        int i = 4 * t + j;
        if (i < nb) {
            S[i] = x;
            float4 s4 = bs4[i];
            double xd = (double)x;
            ds  += (double)s4.x * xd + (double)s4.y;
            ds2 += (double)s4.z * xd * xd + 2.0 * (double)s4.w * xd + (double)bs1[i];
        }
        x = la[j] * x + lb[j];
    }
    dS[t] = ds; dS2[t] = ds2;
    __syncthreads();
    for (int dd = BLOCK / 2; dd > 0; dd >>= 1) {
        if (t < dd) { dS[t] += dS[t + dd]; dS2[t] += dS2[t + dd]; }
        __syncthreads();
    }
    if (t == 0) {
        double sum = dS[0], sumsq = dS2[0];
        double mean = sum / (double)n;
        double var = (sumsq - sum * sum / (double)n) / (double)(n - 1);
        if (var < 0.0) var = 0.0;
        stats[0] = (float)mean;
        stats[1] = 1.0f / ((float)sqrt(var) + 1e-9f);
    }
}

// ---------------- K3: replay + finalize; pure float4 stores ----------------
__global__ __launch_bounds__(BLOCK) void k3_final(
    const float* __restrict__ rewards, const float* __restrict__ values,
    const float* __restrict__ next_values, const void* __restrict__ term,
    const void* __restrict__ trunc, const float* __restrict__ lp,
    const float* __restrict__ olp, const float* __restrict__ S,
    const float* __restrict__ stats, float* __restrict__ out, int n)
{
    __shared__ int flg[2];
    __shared__ float sA[BLOCK], sB[BLOCK];
    int mode = detect_mode(term, n, flg);
    int t = threadIdx.x;
    long base = (long)blockIdx.x * CHUNK + (long)t * ITEMS;
    float c[ITEMS], d[ITEMS], v[ITEMS];
    compute_cd(rewards, values, next_values, term, trunc, mode, base, n, c, d, v);
    float a = 1.f, b = 0.f;
#pragma unroll
    for (int j = ITEMS - 1; j >= 0; --j) { b = c[j]*b + d[j]; a = c[j]*a; }
    sA[t] = a; sB[t] = b;
    __syncthreads();
    for (int dd = 1; dd < BLOCK; dd <<= 1) {
        float ra = 1.f, rb = 0.f;
        if (t + dd < BLOCK) { ra = sA[t + dd]; rb = sB[t + dd]; }
        __syncthreads();
        b = a * rb + b;
        a = a * ra;
        sA[t] = a; sB[t] = b;
        __syncthreads();
    }
    float ea = 1.f, eb = 0.f;
    if (t + 1 < BLOCK) { ea = sA[t + 1]; eb = sB[t + 1]; }
    float x = ea * S[blockIdx.x] + eb;
    float adv[ITEMS];
#pragma unroll
    for (int j = ITEMS - 1; j >= 0; --j) {
        x = c[j] * x + d[j];
        adv[j] = x;
    }
    const float mean = stats[0];
    const float inv  = stats[1];
    if (base + ITEMS <= n) {
        float l[ITEMS], o[ITEMS];
        const float4* l4 = (const float4*)(lp + base);
        const float4* o4 = (const float4*)(olp + base);
#pragma unroll
        for (int k = 0; k < 2; ++k) {
            float4 q = l4[k]; l[4*k]=q.x; l[4*k+1]=q.y; l[4*k+2]=q.z; l[4*k+3]=q.w;
            float4 w = o4[k]; o[4*k]=w.x; o[4*k+1]=w.y; o[4*k+2]=w.z; o[4*k+3]=w.w;
        }
        float buf[3 * ITEMS];
#pragma unroll
        for (int j = 0; j < ITEMS; ++j) {
            float an = (adv[j] - mean) * inv;
            float ratio = expf(l[j] - o[j]);
            float cl = fminf(fmaxf(ratio, 0.8f), 1.2f);
            buf[3*j]     = an;
            buf[3*j + 1] = adv[j] + v[j];
            buf[3*j + 2] = -fminf(ratio * an, cl * an);
        }
        float4* dst = (float4*)(out + 3 * base);   // 3*base % 4 == 0 → 16B aligned
#pragma unroll
        for (int k = 0; k < 6; ++k)
            dst[k] = make_float4(buf[4*k], buf[4*k+1], buf[4*k+2], buf[4*k+3]);
    } else {
        for (int j = 0; j < ITEMS; ++j) {
            long i = base + j;
            if (i < (long)n) {
                float an = (adv[j] - mean) * inv;
                float ratio = expf(lp[i] - olp[i]);
                float cl = fminf(fmaxf(ratio, 0.8f), 1.2f);
                out[3*i]     = an;
                out[3*i + 1] = adv[j] + v[j];
                out[3*i + 2] = -fminf(ratio * an, cl * an);
            }
        }
    }
}

extern "C" void kernel_launch(void* const* d_in, const int* in_sizes, int n_in,
                              void* d_out, int out_size, void* d_ws, size_t ws_size,
                              hipStream_t stream) {
    const float* rewards     = (const float*)d_in[0];
    const float* values      = (const float*)d_in[1];
    const float* next_values = (const float*)d_in[2];
    const float* lp          = (const float*)d_in[3];
    const float* olp         = (const float*)d_in[4];
    const void*  term        = d_in[5];
    const void*  trunc       = d_in[6];
    float* out = (float*)d_out;
    int n = in_sizes[0];
    int nb = (n + CHUNK - 1) / CHUNK;   // 1024 for N=2^21; must be <= MAXNB

    char* ws = (char*)d_ws;
    float2* blockAgg = (float2*)ws;                               // 8 KB
    float4* bs4      = (float4*)(ws + MAXNB * 8);                 // 16 KB
    float*  bs1      = (float*) (ws + MAXNB * 8 + MAXNB * 16);    // 4 KB
    float*  S        = (float*) (ws + MAXNB * 8 + MAXNB * 16 + MAXNB * 4);
    float*  stats    = (float*) (ws + MAXNB * 8 + MAXNB * 16 + MAXNB * 4 + MAXNB * 4);

    k1_agg <<<nb, BLOCK, 0, stream>>>(rewards, values, next_values, term, trunc,
                                      blockAgg, bs4, bs1, n);
    k2_scan<<<1,  BLOCK, 0, stream>>>(blockAgg, bs4, bs1, S, stats, nb, n);
    k3_final<<<nb, BLOCK, 0, stream>>>(rewards, values, next_values, term, trunc,
                                       lp, olp, S, stats, out, n);
}